// Round 1
// 144.058 us; speedup vs baseline: 1.0516x; 1.0516x over previous
//
#include <hip/hip_runtime.h>
#include <math.h>

// B=4, T=4096, C=1024, H=64. fp32 in/out, bf16 MFMA internally.
// K1 wtrans_zero: W (C,H) fp32 -> WT bf16 [192][1024]; zero the attn accumulator.
// K2 qkv_proj: x -> k bf16 [BT][64]; q bf16 [BT][64] PRE-SCALED by 1/8 (exact in
//              bf16); v transposed bf16 [b][64][T], stored as packed us4 (the 4
//              accumulator regs are 4 consecutive t at fixed h = contiguous).
// K3 attn: no-max softmax. S^T computed via swapped mfma(K,Q) so each lane holds
//          P[kk][q=l16]; P->bf16 A-fragments built IN REGISTER with
//          v_cvt_pk_bf16_f32 + v_permlane32/16_swap_b32 (no Ps LDS round-trip).
//          O and l=sum(p) are linear in kv chunks; 640 balanced chunk-blocks
//          atomicAdd fp32 partials into acc[row][68] (col 64 = l via ones-row).
// K4 normalize: out = acc[:, :64] / acc[:, 64].

#define BT   16384
#define TDIM 4096
#define CDIM 1024
#define HDIM 64
#define ACCW 68           // acc row stride (floats); col 64 holds l

typedef __attribute__((ext_vector_type(8))) short bf16x8;
typedef __attribute__((ext_vector_type(4))) float f32x4;
typedef __attribute__((ext_vector_type(8))) unsigned short us8;
typedef __attribute__((ext_vector_type(4))) unsigned short us4;

static __device__ __forceinline__ unsigned short f2bf(float f) {
    unsigned int u = __float_as_uint(f);
    u += 0x7fffu + ((u >> 16) & 1u);
    return (unsigned short)(u >> 16);
}

// Chained lane-swap: after pswap(x,y),
//   x = [X(q0), X(q2), Y(q0), Y(q2)]  per quad, y = [X(q1), X(q3), Y(q1), Y(q3)]
// which is exactly A-frag word w (x) and word w+2 (y) when X=c[st_lo][h],
// Y=c[st_hi][h].
static __device__ __forceinline__ void pswap(unsigned &x, unsigned &y) {
    asm("v_permlane32_swap_b32 %0, %1" : "+v"(x), "+v"(y));
    asm("v_permlane16_swap_b32 %0, %1" : "+v"(x), "+v"(y));
}

// ---------------- K1: W transpose->bf16 + acc zero ----------------
__global__ __launch_bounds__(256) void wtrans_zero(
    const float* __restrict__ Wk, const float* __restrict__ Wq,
    const float* __restrict__ Wv, unsigned short* __restrict__ wtg,
    float* __restrict__ accp)
{
    int idx = blockIdx.x * 256 + threadIdx.x;     // 0..196607
    int mat = idx >> 16;
    int rem = idx & 65535;
    int h = rem >> 10, c = rem & 1023;
    const float* W = (mat == 0) ? Wk : (mat == 1) ? Wq : Wv;
    wtg[idx] = f2bf(W[c * HDIM + h]);             // WT[mat*64+h][c]
    for (int i = idx; i < BT * ACCW; i += 196608) accp[i] = 0.f;
}

// ---------------- K2: QKV projection ----------------
__global__ __launch_bounds__(512) void qkv_proj(
    const float* __restrict__ x, const unsigned short* __restrict__ wtg,
    unsigned short* __restrict__ kg, unsigned short* __restrict__ qg,
    unsigned short* __restrict__ vtg)
{
    __shared__ __align__(16) unsigned short xs[32][72];
    __shared__ __align__(16) unsigned short wts[192][72];
    const int t = threadIdx.x;
    const int lane = t & 63, wv = t >> 6, quad = lane >> 4, l16 = lane & 15;
    const int mt = wv >> 2;                  // m-tile 0/1 (16 rows each)
    const int nq = wv & 3;                   // n-quarter: n-tiles nq*3..nq*3+2
    const int row0 = blockIdx.x * 32;

    const int xr = t >> 4, xc4 = (t & 15) * 4;       // x: 1 float4/thread
    const int wn = t >> 3, wc8 = (t & 7) * 8;        // WT: 3 us8/thread

    f32x4 acc3[3];
    #pragma unroll
    for (int i = 0; i < 3; i++) acc3[i] = (f32x4){0.f, 0.f, 0.f, 0.f};

    float4 xv = *(const float4*)&x[(size_t)(row0 + xr) * CDIM + xc4];
    us8 w0 = *(const us8*)&wtg[(size_t)(wn +   0) * CDIM + wc8];
    us8 w1 = *(const us8*)&wtg[(size_t)(wn +  64) * CDIM + wc8];
    us8 w2 = *(const us8*)&wtg[(size_t)(wn + 128) * CDIM + wc8];

    for (int cc = 0; cc < CDIM; cc += 64) {
        __syncthreads();
        us4 pk = { f2bf(xv.x), f2bf(xv.y), f2bf(xv.z), f2bf(xv.w) };
        *(us4*)&xs[xr][xc4] = pk;
        *(us8*)&wts[wn +   0][wc8] = w0;
        *(us8*)&wts[wn +  64][wc8] = w1;
        *(us8*)&wts[wn + 128][wc8] = w2;
        __syncthreads();
        if (cc + 64 < CDIM) {
            int nc = cc + 64;
            xv = *(const float4*)&x[(size_t)(row0 + xr) * CDIM + nc + xc4];
            w0 = *(const us8*)&wtg[(size_t)(wn +   0) * CDIM + nc + wc8];
            w1 = *(const us8*)&wtg[(size_t)(wn +  64) * CDIM + nc + wc8];
            w2 = *(const us8*)&wtg[(size_t)(wn + 128) * CDIM + nc + wc8];
        }
        bf16x8 a0 = *(const bf16x8*)&xs[mt * 16 + l16][quad * 8];
        bf16x8 a1 = *(const bf16x8*)&xs[mt * 16 + l16][32 + quad * 8];
        #pragma unroll
        for (int j = 0; j < 3; j++) {
            int nt = nq * 3 + j;
            bf16x8 b0 = *(const bf16x8*)&wts[nt * 16 + l16][quad * 8];
            bf16x8 b1 = *(const bf16x8*)&wts[nt * 16 + l16][32 + quad * 8];
            acc3[j] = __builtin_amdgcn_mfma_f32_16x16x32_bf16(a0, b0, acc3[j], 0, 0, 0);
            acc3[j] = __builtin_amdgcn_mfma_f32_16x16x32_bf16(a1, b1, acc3[j], 0, 0, 0);
        }
    }

    const int mrow = row0 + mt * 16 + quad * 4;
    #pragma unroll
    for (int j = 0; j < 3; j++) {
        int nt = nq * 3 + j;
        int mat = nt >> 2;
        int col = (nt & 3) * 16 + l16;
        if (mat == 2) {
            // V: 4 regs are 4 consecutive t at fixed h -> contiguous in vtg
            int bb = mrow >> 12, tr = mrow & 4095;   // 4 rows never cross batch
            us4 pv = { f2bf(acc3[j][0]), f2bf(acc3[j][1]),
                       f2bf(acc3[j][2]), f2bf(acc3[j][3]) };
            *(us4*)&vtg[((size_t)(bb * HDIM + col) << 12) + tr] = pv;
        } else {
            // Q is pre-scaled by 1/8 (exact power-of-2 in bf16)
            float s = (mat == 1) ? 0.125f : 1.0f;
            unsigned short* dst = (mat == 0) ? kg : qg;
            #pragma unroll
            for (int reg = 0; reg < 4; reg++)
                dst[(size_t)(mrow + reg) * HDIM + col] = f2bf(acc3[j][reg] * s);
        }
    }
}

// ---------------- K3: chunked flash attention (no-max softmax) ----------------
__global__ __launch_bounds__(256) void attn(
    const unsigned short* __restrict__ qg, const unsigned short* __restrict__ kg,
    const unsigned short* __restrict__ vtg, float* __restrict__ accp)
{
    __shared__ __align__(16) unsigned short Ks[64][72];
    __shared__ __align__(16) unsigned short Vt[80][72];   // rows 64..79: ones/zeros

    const int t = threadIdx.x;
    const int lane = t & 63, wv = t >> 6, quad = lane >> 4, l16 = lane & 15;

    // blockIdx -> (batch b, q-tile qt, kv-chunk c); 160 chunk-slots per batch
    const int b = blockIdx.x / 160;
    const int s = blockIdx.x - b * 160;
    int qt, c;
    if (s < 16)      { qt = s;               c = 0; }
    else if (s < 48) { int u = s - 16; qt = 16 + (u >> 1); c = u & 1; }
    else if (s < 96) { int u = s - 48; int q3 = u / 3; qt = 32 + q3; c = u - 3 * q3; }
    else             { int u = s - 96; qt = 48 + (u >> 2); c = u & 3; }

    const size_t bbase = (size_t)b * TDIM;
    const int Q0 = qt * 64;
    const int kt0 = c * 16;
    const int kt1 = (kt0 + 15 < qt) ? kt0 + 15 : qt;

    // init constant rows of Vt (row 64 = 1.0 bf16, rows 65..79 = 0)
    for (int i = t; i < 16 * 72; i += 256) {
        int r = i / 72, cc = i - r * 72;
        Vt[64 + r][cc] = (r == 0) ? (unsigned short)0x3F80 : (unsigned short)0;
    }

    // Q fragments (used as B-operand in swapped QK^T: n=l16 is the q-row)
    const int qrow = Q0 + wv * 16 + l16;
    bf16x8 qa0 = *(const bf16x8*)&qg[(bbase + qrow) * HDIM + quad * 8];
    bf16x8 qa1 = *(const bf16x8*)&qg[(bbase + qrow) * HDIM + 32 + quad * 8];

    f32x4 O[5];
    #pragma unroll
    for (int i = 0; i < 5; i++) O[i] = (f32x4){0.f, 0.f, 0.f, 0.f};

    const int fr = t >> 3, fc = (t & 7) * 8;

    us8 kr0 = *(const us8*)&kg[(bbase + kt0 * 64 + fr) * HDIM + fc];
    us8 kr1 = *(const us8*)&kg[(bbase + kt0 * 64 + fr + 32) * HDIM + fc];
    us8 vr0 = *(const us8*)&vtg[((size_t)(b * HDIM + fr) << 12) + kt0 * 64 + fc];
    us8 vr1 = *(const us8*)&vtg[((size_t)(b * HDIM + fr + 32) << 12) + kt0 * 64 + fc];

    const int qloc = wv * 16 + l16;        // this lane's q row, Q-tile-local
    for (int kt = kt0; kt <= kt1; kt++) {
        __syncthreads();
        *(us8*)&Ks[fr][fc] = kr0;
        *(us8*)&Ks[fr + 32][fc] = kr1;
        *(us8*)&Vt[fr][fc] = vr0;
        *(us8*)&Vt[fr + 32][fc] = vr1;
        __syncthreads();
        if (kt < kt1) {
            int kn = kt + 1;
            kr0 = *(const us8*)&kg[(bbase + kn * 64 + fr) * HDIM + fc];
            kr1 = *(const us8*)&kg[(bbase + kn * 64 + fr + 32) * HDIM + fc];
            vr0 = *(const us8*)&vtg[((size_t)(b * HDIM + fr) << 12) + kn * 64 + fc];
            vr1 = *(const us8*)&vtg[((size_t)(b * HDIM + fr + 32) << 12) + kn * 64 + fc];
        }

        // S^T = K Q^T (swapped operands): lane holds S[kk=st*16+quad*4+r][q=l16]
        f32x4 sT[4];
        #pragma unroll
        for (int st = 0; st < 4; st++) {
            bf16x8 kb0 = *(const bf16x8*)&Ks[st * 16 + l16][quad * 8];
            bf16x8 kb1 = *(const bf16x8*)&Ks[st * 16 + l16][32 + quad * 8];
            f32x4 z = (f32x4){0.f, 0.f, 0.f, 0.f};
            z = __builtin_amdgcn_mfma_f32_16x16x32_bf16(kb0, qa0, z, 0, 0, 0);
            z = __builtin_amdgcn_mfma_f32_16x16x32_bf16(kb1, qa1, z, 0, 0, 0);
            sT[st] = z;
        }

        // p = exp(s) (q pre-scaled by 1/8); causal mask: zero where kk > q
        const bool diag = (kt == qt);
        float p[4][4];
        #pragma unroll
        for (int st = 0; st < 4; st++) {
            #pragma unroll
            for (int r = 0; r < 4; r++) {
                int kkloc = st * 16 + quad * 4 + r;
                p[st][r] = (diag && (kkloc > qloc)) ? 0.f : __expf(sT[st][r]);
            }
        }

        // pack pairs to bf16, then permlane-swap into PV A-fragment layout
        unsigned cpk[4][2];
        #pragma unroll
        for (int st = 0; st < 4; st++) {
            asm("v_cvt_pk_bf16_f32 %0, %1, %2"
                : "=v"(cpk[st][0]) : "v"(p[st][0]), "v"(p[st][1]));
            asm("v_cvt_pk_bf16_f32 %0, %1, %2"
                : "=v"(cpk[st][1]) : "v"(p[st][2]), "v"(p[st][3]));
        }
        union { unsigned u[4]; bf16x8 v; } pa0u, pa1u;
        {
            unsigned a0 = cpk[0][0], b0 = cpk[1][0]; pswap(a0, b0);
            unsigned a1 = cpk[0][1], b1 = cpk[1][1]; pswap(a1, b1);
            pa0u.u[0] = a0; pa0u.u[1] = a1; pa0u.u[2] = b0; pa0u.u[3] = b1;
            unsigned a2 = cpk[2][0], b2 = cpk[3][0]; pswap(a2, b2);
            unsigned a3 = cpk[2][1], b3 = cpk[3][1]; pswap(a3, b3);
            pa1u.u[0] = a2; pa1u.u[1] = a3; pa1u.u[2] = b2; pa1u.u[3] = b3;
        }
        const bf16x8 pa0 = pa0u.v, pa1 = pa1u.v;

        // O += P V
        #pragma unroll
        for (int nt = 0; nt < 5; nt++) {
            bf16x8 vb0 = *(const bf16x8*)&Vt[nt * 16 + l16][quad * 8];
            bf16x8 vb1 = *(const bf16x8*)&Vt[nt * 16 + l16][32 + quad * 8];
            O[nt] = __builtin_amdgcn_mfma_f32_16x16x32_bf16(pa0, vb0, O[nt], 0, 0, 0);
            O[nt] = __builtin_amdgcn_mfma_f32_16x16x32_bf16(pa1, vb1, O[nt], 0, 0, 0);
        }
    }

    // flush partials: acc[row][col] += O ; acc[row][64] += l
    const int grow = (b << 12) + Q0 + wv * 16 + quad * 4;
    #pragma unroll
    for (int nt = 0; nt < 4; nt++)
        #pragma unroll
        for (int r = 0; r < 4; r++)
            atomicAdd(&accp[(size_t)(grow + r) * ACCW + nt * 16 + l16], O[nt][r]);
    if (l16 == 0) {
        #pragma unroll
        for (int r = 0; r < 4; r++)
            atomicAdd(&accp[(size_t)(grow + r) * ACCW + 64], O[4][r]);
    }
}

// ---------------- K4: normalize ----------------
__global__ __launch_bounds__(256) void normalize(
    const float* __restrict__ accp, float* __restrict__ out)
{
    int idx = blockIdx.x * 256 + threadIdx.x;   // 262144 = 16384 rows * 16 float4
    int row = idx >> 4, c4 = (idx & 15) * 4;
    float inv = 1.f / accp[(size_t)row * ACCW + 64];
    float4 o = *(const float4*)&accp[(size_t)row * ACCW + c4];
    float4 res = make_float4(o.x * inv, o.y * inv, o.z * inv, o.w * inv);
    *(float4*)&out[(size_t)row * HDIM + c4] = res;
}

extern "C" void kernel_launch(void* const* d_in, const int* in_sizes, int n_in,
                              void* d_out, int out_size, void* d_ws, size_t ws_size,
                              hipStream_t stream) {
    const float* x  = (const float*)d_in[0];
    const float* Wk = (const float*)d_in[1];
    const float* Wq = (const float*)d_in[2];
    const float* Wv = (const float*)d_in[3];
    float* out = (float*)d_out;

    unsigned short* wtg = (unsigned short*)d_ws;        // [192][1024] bf16
    unsigned short* kg  = wtg + 196608;                 // [BT][64] bf16
    unsigned short* qg  = kg + (size_t)BT * HDIM;       // [BT][64] bf16 (q/8)
    unsigned short* vtg = qg + (size_t)BT * HDIM;       // [4][64][4096] bf16
    float* accp = (float*)(vtg + (size_t)4 * HDIM * TDIM);  // [BT][68] fp32

    wtrans_zero<<<768, 256, 0, stream>>>(Wk, Wq, Wv, wtg, accp);
    qkv_proj<<<BT / 32, 512, 0, stream>>>(x, wtg, kg, qg, vtg);
    attn<<<4 * 160, 256, 0, stream>>>(qg, kg, vtg, accp);
    normalize<<<BT * HDIM / (4 * 256), 256, 0, stream>>>(accp, out);
}